// Round 8
// baseline (150.551 us; speedup 1.0000x reference)
//
#include <hip/hip_runtime.h>
#include <cstdint>
#include <cstddef>

#define LRALPHA 0.1f
static constexpr int NR = 8192;      // N and Na
static constexpr int EF = 256;
static constexpr int IN_F = 512;
static constexpr int OUT_F = 512;
static constexpr int KP2 = 1024;     // fp16 split-2, k'-interleaved [ah,al]
static constexpr int NCH = 128;      // chunks for column scans
static constexpr int CHR = 64;       // rows per chunk (NCH*CHR = 8192)

typedef __attribute__((ext_vector_type(8))) _Float16 f16x8;
typedef __attribute__((ext_vector_type(4))) float f32x4;

// ---- fused prep: s1/s2 dots (blocks 0..4095) + B pack (blocks 4096..5119) ----
__global__ __launch_bounds__(256) void k_prep(const float* __restrict__ feat_edge,
                                              const float* __restrict__ feat_edge_a,
                                              const float* __restrict__ att,
                                              const float* __restrict__ W,
                                              float* __restrict__ s1,
                                              float* __restrict__ s2,
                                              short* __restrict__ B3t) {
  int b = blockIdx.x;
  if (b < 4096) {
    int vrow = b * 4 + (threadIdx.x >> 6);
    int lane = threadIdx.x & 63;
    const float* feat; const float* av; float* outp; int row;
    if (vrow < NR) { row = vrow; feat = feat_edge; av = att; outp = s1; }
    else { row = vrow - NR; feat = feat_edge_a; av = att + EF; outp = s2; }
    float4 f = reinterpret_cast<const float4*>(feat + (size_t)row * EF)[lane];
    float4 a = reinterpret_cast<const float4*>(av)[lane];
    float d = f.x * a.x + f.y * a.y + f.z * a.z + f.w * a.w;
#pragma unroll
    for (int off = 32; off > 0; off >>= 1) d += __shfl_xor(d, off);
    if (lane == 0) outp[row] = d;
  } else {
    int i = (b - 4096) * 256 + threadIdx.x;  // < 512*512
    int n = i >> 9, k = i & 511;
    float x = W[(size_t)k * OUT_F + n];
    _Float16 h = (_Float16)x;
    unsigned short u = __builtin_bit_cast(unsigned short, h);
    unsigned int w = (unsigned int)u | ((unsigned int)u << 16);
    *reinterpret_cast<unsigned int*>(B3t + (size_t)n * KP2 + 2 * k) = w;
  }
}

// ---- Wh = split2(A) @ B3t^T : BARRIER-FREE direct-to-register GEMM ----
// Each wave: 32x32 output tile; A/B fragments loaded straight from global
// (coalesced 64B per 16-row group), A split to [ah|al] f16 in-register.
// No LDS, no __syncthreads -> nothing ever drains the load pipeline; the
// compiler emits counted vmcnt per dependency and 16 waves/CU give TLP.
// XCD-chunk swizzle: each XCD works on 16 m-bands x all 8 n-blocks ->
// its 2MB A-chunk + 1MB B stay L2-resident.
__global__ __launch_bounds__(256, 4) void k_gemm(const float* __restrict__ A,
                                                 const short* __restrict__ B3t,
                                                 float* __restrict__ Wh) {
  int bid = blockIdx.x;                       // 0..1023
  int lbid = (bid & 7) * 128 + (bid >> 3);    // XCD-chunk swizzle (bijective)
  int mb = lbid >> 3, nb = lbid & 7;
  const int tid = threadIdx.x;
  const int wid = tid >> 6, lane = tid & 63;
  const int wr = wid >> 1, wc = wid & 1;
  const int rbase = mb * 64 + wr * 32;
  const int cbase = nb * 64 + wc * 32;
  const int fr = lane & 15, g = lane >> 4;

  const float* pa0 = A + (size_t)(rbase + fr) * IN_F + g * 4;
  const float* pa1 = pa0 + 16 * IN_F;
  const short* pb0 = B3t + (size_t)(cbase + fr) * KP2 + g * 8;
  const short* pb1 = pb0 + 16 * KP2;

  f32x4 a00 = {}, a01 = {}, a10 = {}, a11 = {};

  auto cvt4 = [](float4 p) -> f16x8 {   // 4 f32 -> [ah0,al0,ah1,al1,ah2,al2,ah3,al3]
    float xs[4] = {p.x, p.y, p.z, p.w};
    f16x8 r;
#pragma unroll
    for (int e = 0; e < 4; ++e) {
      _Float16 h = (_Float16)xs[e];
      _Float16 l = (_Float16)(xs[e] - (float)h);
      r[2 * e] = h; r[2 * e + 1] = l;
    }
    return r;
  };

#pragma unroll 4
  for (int ks = 0; ks < 32; ++ks) {
    float4 fa0 = *reinterpret_cast<const float4*>(pa0 + ks * 16);
    float4 fa1 = *reinterpret_cast<const float4*>(pa1 + ks * 16);
    f16x8 b0 = *reinterpret_cast<const f16x8*>(pb0 + ks * 32);
    f16x8 b1 = *reinterpret_cast<const f16x8*>(pb1 + ks * 32);
    f16x8 af0 = cvt4(fa0), af1 = cvt4(fa1);
    a00 = __builtin_amdgcn_mfma_f32_16x16x32_f16(af0, b0, a00, 0, 0, 0);
    a01 = __builtin_amdgcn_mfma_f32_16x16x32_f16(af0, b1, a01, 0, 0, 0);
    a10 = __builtin_amdgcn_mfma_f32_16x16x32_f16(af1, b0, a10, 0, 0, 0);
    a11 = __builtin_amdgcn_mfma_f32_16x16x32_f16(af1, b1, a11, 0, 0, 0);
  }

  // C/D layout: row=(lane>>4)*4+reg, col=lane&15 (verified R1-R7)
  int orow = rbase + g * 4;
  int ocol = cbase + fr;
#pragma unroll
  for (int r = 0; r < 4; ++r) {
    Wh[(size_t)(orow + r) * OUT_F + ocol]           = a00[r];
    Wh[(size_t)(orow + r) * OUT_F + ocol + 16]      = a01[r];
    Wh[(size_t)(orow + 16 + r) * OUT_F + ocol]      = a10[r];
    Wh[(size_t)(orow + 16 + r) * OUT_F + ocol + 16] = a11[r];
  }
}

// ---- rank-by-counting: 8 lanes per key, L2-resident reads ----
__global__ __launch_bounds__(256) void k_rank(const float* __restrict__ s2,
                                              float* __restrict__ s2s, int* __restrict__ perm) {
  int t = threadIdx.x;
  int ki = blockIdx.x * 32 + (t >> 3);   // 256 blocks x 32 keys
  int part = t & 7;                      // 8 lanes share one key
  float key = s2[ki];
  int rank = 0;
  const float4* p = reinterpret_cast<const float4*>(s2) + part * 256;  // 1024 floats per part
  int jbase = part * 1024;
#pragma unroll 4
  for (int q = 0; q < 256; ++q) {
    float4 v = p[q];
    int j = jbase + q * 4;
    rank += (v.x < key) || (v.x == key && (j + 0) < ki);
    rank += (v.y < key) || (v.y == key && (j + 1) < ki);
    rank += (v.z < key) || (v.z == key && (j + 2) < ki);
    rank += (v.w < key) || (v.w == key && (j + 3) < ki);
  }
  rank += __shfl_xor(rank, 1);
  rank += __shfl_xor(rank, 2);
  rank += __shfl_xor(rank, 4);
  if (part == 0) { s2s[rank] = key; perm[rank] = ki; }
}

// ---- scalar suffix(exp(s2s)) and prefix(exp(a*s2s)) sums + ea/eb tables ----
__global__ __launch_bounds__(1024) void k_scan_scalar(const float* __restrict__ s2s,
                                                      float* __restrict__ sufa,
                                                      float* __restrict__ preb,
                                                      float* __restrict__ eaA,
                                                      float* __restrict__ ebA) {
  __shared__ float pa[1024], pb[1024];
  int t = threadIdx.x;
  float ea[8], eb[8];
  float sa = 0.f, sb = 0.f;
#pragma unroll
  for (int e = 0; e < 8; ++e) {
    float kk = s2s[t * 8 + e];
    ea[e] = expf(kk);
    eb[e] = expf(LRALPHA * kk);
    eaA[t * 8 + e] = ea[e];
    ebA[t * 8 + e] = eb[e];
    sa += ea[e]; sb += eb[e];
  }
  pa[t] = sa; pb[t] = sb;
  __syncthreads();
  for (int off = 1; off < 1024; off <<= 1) {  // Hillis-Steele, pb fwd / pa bwd
    float addb = (t >= off) ? pb[t - off] : 0.f;
    float adda = (t + off < 1024) ? pa[t + off] : 0.f;
    __syncthreads();
    pb[t] += addb; pa[t] += adda;
    __syncthreads();
  }
  float base_b = (t > 0) ? pb[t - 1] : 0.f;       // sum over threads < t
  float base_a = (t < 1023) ? pa[t + 1] : 0.f;    // sum over threads > t
  float run = base_b;
#pragma unroll
  for (int e = 0; e < 8; ++e) { preb[t * 8 + e] = run; run += eb[e]; }
  if (t == 1023) preb[NR] = run;
  run = base_a;
#pragma unroll
  for (int e = 7; e >= 0; --e) { run += ea[e]; sufa[t * 8 + e] = run; }
  if (t == 1023) sufa[NR] = 0.f;
}

// ---- column scans over Wh[perm] with precomputed ea/eb weights ----
__global__ __launch_bounds__(256) void k_passA(const float* __restrict__ Wh,
                                               const float* __restrict__ eaA,
                                               const float* __restrict__ ebA,
                                               const int* __restrict__ perm,
                                               float* __restrict__ chunkA, float* __restrict__ chunkB) {
  int chunk = blockIdx.x;
  int col = blockIdx.y * 256 + threadIdx.x;
  float accA = 0.f, accB = 0.f;
  int r0 = chunk * CHR;
  for (int rl = 0; rl < CHR; ++rl) {
    int r = r0 + rl;
    float v = Wh[(size_t)perm[r] * OUT_F + col];
    accA += eaA[r] * v;
    accB += ebA[r] * v;
  }
  chunkA[chunk * OUT_F + col] = accA;
  chunkB[chunk * OUT_F + col] = accB;
}

__global__ __launch_bounds__(256) void k_passB(const float* __restrict__ chunkA,
                                               const float* __restrict__ chunkB,
                                               float* __restrict__ baseA, float* __restrict__ baseB) {
  int col = blockIdx.x * 256 + threadIdx.x;
  float run = 0.f;
  for (int c = NCH - 1; c >= 0; --c) { baseA[c * OUT_F + col] = run; run += chunkA[c * OUT_F + col]; }
  run = 0.f;
  for (int c = 0; c < NCH; ++c) { baseB[c * OUT_F + col] = run; run += chunkB[c * OUT_F + col]; }
}

__global__ __launch_bounds__(256) void k_passC(const float* __restrict__ Wh,
                                               const float* __restrict__ eaA,
                                               const float* __restrict__ ebA,
                                               const int* __restrict__ perm,
                                               const float* __restrict__ baseA,
                                               const float* __restrict__ baseB,
                                               float* __restrict__ SufA, float* __restrict__ PreB) {
  int chunk = blockIdx.x;
  int col = blockIdx.y * 256 + threadIdx.x;
  int r0 = chunk * CHR;
  float bA = baseA[chunk * OUT_F + col];
  float bB = baseB[chunk * OUT_F + col];
  float acc = 0.f;
  for (int rl = CHR - 1; rl >= 0; --rl) {   // suffix incl.
    int r = r0 + rl;
    float v = Wh[(size_t)perm[r] * OUT_F + col];
    acc += eaA[r] * v;
    SufA[(size_t)r * OUT_F + col] = acc + bA;
  }
  acc = 0.f;
  for (int rl = 0; rl < CHR; ++rl) {        // prefix excl.
    int r = r0 + rl;
    float v = Wh[(size_t)perm[r] * OUT_F + col];
    PreB[(size_t)r * OUT_F + col] = acc + bB;
    acc += ebA[r] * v;
  }
  if (chunk == NCH - 1) {
    SufA[(size_t)NR * OUT_F + col] = 0.f;
    PreB[(size_t)NR * OUT_F + col] = acc + bB;
  }
}

// ---- per-row: binary search threshold rank, combine, elu ----
__global__ __launch_bounds__(256) void k_final(const float* __restrict__ s1,
                                               const float* __restrict__ s2s,
                                               const float* __restrict__ sufa,
                                               const float* __restrict__ preb,
                                               const float* __restrict__ SufA,
                                               const float* __restrict__ PreB,
                                               float* __restrict__ out) {
  int row = blockIdx.x * 4 + (threadIdx.x >> 6);
  int lane = threadIdx.x & 63;
  float sv = s1[row];
  float t = -sv;
  int lo = 0, hi = NR;
  while (lo < hi) {  // first index with s2s[idx] > t
    int mid = (lo + hi) >> 1;
    if (s2s[mid] > t) hi = mid; else lo = mid + 1;
  }
  float E1 = expf(sv), E1a = expf(LRALPHA * sv);
  float Z = E1 * sufa[lo] + E1a * preb[lo];
  const float* rA = SufA + (size_t)lo * OUT_F;
  const float* rB = PreB + (size_t)lo * OUT_F;
#pragma unroll
  for (int e = 0; e < 8; ++e) {
    int kc = e * 64 + lane;
    float num = E1 * rA[kc] + E1a * rB[kc];
    float h = num / Z;
    out[(size_t)row * OUT_F + kc] = (h > 0.f) ? h : expm1f(h);
  }
}

extern "C" void kernel_launch(void* const* d_in, const int* in_sizes, int n_in,
                              void* d_out, int out_size, void* d_ws, size_t ws_size,
                              hipStream_t stream) {
  (void)in_sizes; (void)n_in; (void)out_size; (void)ws_size;
  const float* feat_edge   = (const float*)d_in[0];
  const float* feat_edge_a = (const float*)d_in[1];
  const float* feat_node_a = (const float*)d_in[2];
  const float* weight      = (const float*)d_in[3];
  const float* att         = (const float*)d_in[4];
  float* out = (float*)d_out;

  char* ws = (char*)d_ws;
  size_t off = 0;
  auto alloc = [&](size_t bytes) { size_t o = off; off += (bytes + 255) & ~(size_t)255; return o; };

  float* Wh = (float*)(ws + alloc((size_t)NR * OUT_F * 4));           // 16.78 MB
  // Region hosts B3t (GEMM phase), then SufA+PreB (scan phase) — disjoint lifetimes.
  size_t regionOff = alloc((size_t)(NR + 1) * OUT_F * 4 * 2);          // 33.56 MB
  float* SufA = (float*)(ws + regionOff);
  float* PreB = (float*)(ws + regionOff + (size_t)(NR + 1) * OUT_F * 4);
  short* B3t  = (short*)(ws + regionOff);                              // 1.05 MB (512x1024 fp16)

  float* s1   = (float*)(ws + alloc(NR * 4));
  float* s2   = (float*)(ws + alloc(NR * 4));
  float* s2s  = (float*)(ws + alloc(NR * 4));
  int*   perm = (int*)  (ws + alloc(NR * 4));
  float* sufa = (float*)(ws + alloc((NR + 1) * 4));
  float* preb = (float*)(ws + alloc((NR + 1) * 4));
  float* eaA  = (float*)(ws + alloc(NR * 4));
  float* ebA  = (float*)(ws + alloc(NR * 4));
  float* chA  = (float*)(ws + alloc(NCH * OUT_F * 4));
  float* chB  = (float*)(ws + alloc(NCH * OUT_F * 4));
  float* bsA  = (float*)(ws + alloc(NCH * OUT_F * 4));
  float* bsB  = (float*)(ws + alloc(NCH * OUT_F * 4));

  k_prep<<<4096 + 1024, 256, 0, stream>>>(feat_edge, feat_edge_a, att, weight, s1, s2, B3t);
  k_gemm<<<1024, 256, 0, stream>>>(feat_node_a, B3t, Wh);
  k_rank<<<NR / 32, 256, 0, stream>>>(s2, s2s, perm);
  k_scan_scalar<<<1, 1024, 0, stream>>>(s2s, sufa, preb, eaA, ebA);
  k_passA<<<dim3(NCH, 2), 256, 0, stream>>>(Wh, eaA, ebA, perm, chA, chB);
  k_passB<<<2, 256, 0, stream>>>(chA, chB, bsA, bsB);
  k_passC<<<dim3(NCH, 2), 256, 0, stream>>>(Wh, eaA, ebA, perm, bsA, bsB, SufA, PreB);
  k_final<<<NR / 4, 256, 0, stream>>>(s1, s2s, sufa, preb, SufA, PreB, out);
}